// Round 22
// baseline (381.163 us; speedup 1.0000x reference)
//
#include <hip/hip_runtime.h>
#include <hip/hip_bf16.h>
#include <math.h>
#include <stdint.h>

// ---------------------------------------------------------------------------
// RatLayer forward. BK=32 dbuf 32KB-LDS bf16 MFMA GEMMs (128^2 skinny) +
// 256^2 MLP GEMMs (gate+up in ONE dual dispatch, 2 blocks/CU, + elementwise
// silu-mul), fused qkv+rope (table), split-K=4 merged wod+wab GEMMs (bf16
// partials) reduced inside rat_write (precomputed tables), rat_write+rat_read
// fusion, merged-pair parallel flash attention (KVBLK=128, bx remap).
// H=1024 C=4 RH=16 HS=64 DR=8 M=4096 NH=16 HD=64 A_SIZE=48 B_SIZE=64
// ---------------------------------------------------------------------------

constexpr int NTOK = 4096;

typedef __attribute__((ext_vector_type(8))) short short8_t;
typedef __attribute__((ext_vector_type(4))) float f32x4;

__device__ __forceinline__ ushort f2bf(float f) {
    union { float f; uint32_t u; } v; v.f = f;
    uint32_t r = v.u + 0x7fffu + ((v.u >> 16) & 1u);
    return (ushort)(r >> 16);
}
__device__ __forceinline__ float bf2f(ushort b) {
    union { uint32_t u; float f; } v; v.u = ((uint32_t)b) << 16;
    return v.f;
}
// packed pair convert — compiler lowers to v_cvt_pk_bf16_f32 on gfx950
__device__ __forceinline__ uint32_t pack2(float lo, float hi) {
    union { __hip_bfloat162 h; uint32_t u; } v;
    v.h = __float22bfloat162_rn(make_float2(lo, hi));
    return v.u;
}
__device__ __forceinline__ float softplus_f(float x) {
    return (x > 20.0f) ? x : log1pf(expf(x));
}

__device__ __forceinline__ void gload_lds16(const void* g, void* l) {
    __builtin_amdgcn_global_load_lds(
        (const __attribute__((address_space(1))) uint32_t*)g,
        (__attribute__((address_space(3))) uint32_t*)l,
        16, 0, 0);
}

// ---------------------------------------------------------------------------
// Weight conversion f32 -> bf16; rope table.
// ---------------------------------------------------------------------------
__global__ __launch_bounds__(256) void convert_flat_kernel(
    const float* __restrict__ src, ushort* __restrict__ dst)
{
    const size_t i = ((size_t)blockIdx.x * 256 + threadIdx.x) * 8;
    const float4 a = *(const float4*)(src + i);
    const float4 b = *(const float4*)(src + i + 4);
    union { ushort u[8]; uint4 v; } o;
    o.u[0] = f2bf(a.x); o.u[1] = f2bf(a.y); o.u[2] = f2bf(a.z); o.u[3] = f2bf(a.w);
    o.u[4] = f2bf(b.x); o.u[5] = f2bf(b.y); o.u[6] = f2bf(b.z); o.u[7] = f2bf(b.w);
    *(uint4*)(dst + i) = o.v;
}

// rope table: tab[pos*32 + i] = (cos, sin) of pos * 10000^(-i/32)
__global__ __launch_bounds__(256) void rope_tab_kernel(float2* __restrict__ tab)
{
    const int idx = blockIdx.x * 256 + threadIdx.x;   // < 2048*32
    const int i = idx & 31;
    const int pos = idx >> 5;
    const float inv = expf(-(float)i * (9.210340371976184f / 32.0f));
    float s, c;
    sincosf((float)pos * inv, &s, &c);
    tab[idx] = make_float2(c, s);
}

// combined weight [1152][K]: rows 0..1023 = wod[0..1023]; 1024..1135 = wab;
// 1136..1143 = wod rows 1024..1031 (delta_low); 1144..1151 = zero.
__global__ __launch_bounds__(256) void build_comb_kernel(
    const float* __restrict__ wod, const float* __restrict__ wab,
    ushort* __restrict__ dst, int K)
{
    const size_t i = ((size_t)blockIdx.x * 256 + threadIdx.x) * 8;
    const int row = (int)(i / (size_t)K);
    const int col = (int)(i % (size_t)K);
    const float* src = nullptr;
    if (row < 1024)      src = wod + (size_t)row * K + col;
    else if (row < 1136) src = wab + (size_t)(row - 1024) * K + col;
    else if (row < 1144) src = wod + (size_t)(1024 + row - 1136) * K + col;
    union { ushort u[8]; uint4 v; } o;
    if (src) {
        const float4 a = *(const float4*)(src);
        const float4 b = *(const float4*)(src + 4);
        o.u[0] = f2bf(a.x); o.u[1] = f2bf(a.y); o.u[2] = f2bf(a.z); o.u[3] = f2bf(a.w);
        o.u[4] = f2bf(b.x); o.u[5] = f2bf(b.y); o.u[6] = f2bf(b.z); o.u[7] = f2bf(b.w);
    } else {
        o.v = make_uint4(0, 0, 0, 0);
    }
    *(uint4*)(dst + i) = o.v;
}

// ---------------------------------------------------------------------------
// silu-mul: up[i] = silu(gate[i]) * up[i], bf16x8 vectorized.
// ---------------------------------------------------------------------------
__global__ __launch_bounds__(256) void silu_mul_kernel(
    const ushort* __restrict__ gate, ushort* __restrict__ up)
{
    const size_t i = ((size_t)blockIdx.x * 256 + threadIdx.x) * 8;
    const uint4 gv = *(const uint4*)(gate + i);
    const uint4 uv = *(const uint4*)(up + i);
    union { uint4 v; ushort u[8]; } g, uu, o;
    g.v = gv; uu.v = uv;
#pragma unroll
    for (int e = 0; e < 8; ++e) {
        const float gf = bf2f(g.u[e]);
        o.u[e] = f2bf(gf / (1.0f + __expf(-gf)) * bf2f(uu.u[e]));
    }
    *(uint4*)(up + i) = o.v;
}

// ---------------------------------------------------------------------------
// rat_read: mix + LayerNorm + affine; writes bf16. One block per token.
// ---------------------------------------------------------------------------
template <int NO>
__global__ __launch_bounds__(256) void rat_read_kernel(
    const float* __restrict__ res, const float* __restrict__ W,
    const float* __restrict__ gamma, const float* __restrict__ beta,
    ushort* __restrict__ out)
{
    const int t = blockIdx.x;
    const int tid = threadIdx.x;
    const float* rp = res + (size_t)t * 4096;
    float y[4][NO];
#pragma unroll
    for (int i = 0; i < 4; ++i) {
        const int h = tid + 256 * i;
        const float4 x = *(const float4*)(rp + h * 4);
#pragma unroll
        for (int o = 0; o < NO; ++o) {
            const float4 w = *(const float4*)(W + ((size_t)h * NO + o) * 4);
            y[i][o] = x.x * w.x + x.y * w.y + x.z * w.z + x.w * w.w;
        }
    }
    __shared__ float red[4][NO][2];
    const int lane = tid & 63, wid = tid >> 6;
#pragma unroll
    for (int o = 0; o < NO; ++o) {
        float s = 0.f, ss = 0.f;
#pragma unroll
        for (int i = 0; i < 4; ++i) { s += y[i][o]; ss += y[i][o] * y[i][o]; }
        for (int off = 32; off > 0; off >>= 1) {
            s += __shfl_down(s, off);
            ss += __shfl_down(ss, off);
        }
        if (lane == 0) { red[wid][o][0] = s; red[wid][o][1] = ss; }
    }
    __syncthreads();
    float mu[NO], rs[NO];
#pragma unroll
    for (int o = 0; o < NO; ++o) {
        const float s  = red[0][o][0] + red[1][o][0] + red[2][o][0] + red[3][o][0];
        const float ss = red[0][o][1] + red[1][o][1] + red[2][o][1] + red[3][o][1];
        const float m = s * (1.0f / 1024.0f);
        const float v = ss * (1.0f / 1024.0f) - m * m;
        mu[o] = m;
        rs[o] = rsqrtf(v + 1e-5f);
    }
    ushort* op = out + (size_t)t * (NO * 1024);
#pragma unroll
    for (int i = 0; i < 4; ++i) {
        const int h = tid + 256 * i;
#pragma unroll
        for (int o = 0; o < NO; ++o) {
            op[o * 1024 + h] = f2bf((y[i][o] - mu[o]) * rs[o] * gamma[o * 1024 + h] + beta[o * 1024 + h]);
        }
    }
}

// ---------------------------------------------------------------------------
// BK=32 dbuf bf16 MFMA GEMM, 128x128 tile, 32KB LDS (5 blocks/CU cap),
// gemm256-pattern staging/swizzle. EPI 4: bf16 partial at Cp + z*NTOK*ldc.
// ---------------------------------------------------------------------------
template <int EPI>
__global__ __launch_bounds__(256) void mfma_gemm_kernel(
    const ushort* __restrict__ A, int lda,
    const ushort* __restrict__ W, int ldw,
    void* __restrict__ Cp, int ldc,
    const ushort* __restrict__ U,
    int Kblk)
{
    __shared__ ushort lds[2][2][128 * 32];   // [buf][A/B][row*32+col] = 32KB
    const int tid = threadIdx.x;
    const int nwg = gridDim.x * gridDim.y;
    const int gy = gridDim.y;
    const int id = blockIdx.y * gridDim.x + blockIdx.x;
    const int swz = (id & 7) * (nwg >> 3) + (id >> 3);
    const int bm = (swz / gy) * 128;
    const int bo = (swz % gy) * 128;

    const int w = tid >> 6, l = tid & 63;
    const int lq = l & 15, lg = l >> 4;
    const int wr = (w >> 1) * 64, wc = (w & 1) * 64;

    f32x4 acc[4][4];
#pragma unroll
    for (int i = 0; i < 4; ++i)
#pragma unroll
        for (int j = 0; j < 4; ++j) acc[i][j] = (f32x4){0.f, 0.f, 0.f, 0.f};

    const int srow = w * 32 + (l >> 2);
    const int schunk = (l & 3) ^ ((l >> 3) & 3);
    const ushort* Ag = A + (size_t)(bm + srow) * lda + (size_t)blockIdx.z * Kblk + schunk * 8;
    const ushort* Wg = W + (size_t)(bo + srow) * ldw + (size_t)blockIdx.z * Kblk + schunk * 8;
    const size_t lda16 = (size_t)16 * lda, ldw16 = (size_t)16 * ldw;

    const int nt = Kblk >> 5;
    int cur = 0;
#pragma unroll
    for (int i = 0; i < 2; ++i) {
        gload_lds16(Ag + i * lda16, &lds[0][0][(w * 32 + i * 16) * 32]);
        gload_lds16(Wg + i * ldw16, &lds[0][1][(w * 32 + i * 16) * 32]);
    }
    __syncthreads();
    for (int t = 0; t < nt; ++t) {
        if (t + 1 < nt) {
            const int k0 = (t + 1) * 32;
#pragma unroll
            for (int i = 0; i < 2; ++i) {
                gload_lds16(Ag + k0 + i * lda16, &lds[cur ^ 1][0][(w * 32 + i * 16) * 32]);
                gload_lds16(Wg + k0 + i * ldw16, &lds[cur ^ 1][1][(w * 32 + i * 16) * 32]);
            }
        }
        short8_t af[4], bf[4];
#pragma unroll
        for (int mf = 0; mf < 4; ++mf) {
            const int ra = wr + mf * 16 + lq;
            af[mf] = *(const short8_t*)&lds[cur][0][ra * 32 + ((lg ^ ((ra >> 1) & 3)) * 8)];
            const int rb = wc + mf * 16 + lq;
            bf[mf] = *(const short8_t*)&lds[cur][1][rb * 32 + ((lg ^ ((rb >> 1) & 3)) * 8)];
        }
        __builtin_amdgcn_s_setprio(1);
#pragma unroll
        for (int mf = 0; mf < 4; ++mf)
#pragma unroll
            for (int nf = 0; nf < 4; ++nf)
                acc[mf][nf] = __builtin_amdgcn_mfma_f32_16x16x32_bf16(
                    af[mf], bf[nf], acc[mf][nf], 0, 0, 0);
        __builtin_amdgcn_s_setprio(0);
        __syncthreads();
        cur ^= 1;
    }

    // EPI 4: bf16 partial via wave-local LDS transpose, full uint4 lines.
    ushort* eb = &lds[0][0][0] + w * 4096;
#pragma unroll
    for (int mf = 0; mf < 4; ++mf)
#pragma unroll
        for (int r = 0; r < 4; ++r)
#pragma unroll
            for (int nf = 0; nf < 4; ++nf) {
                const int rl = mf * 16 + lg * 4 + r;
                const int cl = nf * 16 + lq;
                eb[rl * 64 + cl] = f2bf(acc[mf][nf][r]);
            }
#pragma unroll
    for (int p = 0; p < 8; ++p) {
        const int rl = p * 8 + (l >> 3);
        const int cl = (l & 7) * 8;
        const uint4 v = *(const uint4*)&eb[rl * 64 + cl];
        ushort* dst = (ushort*)Cp + ((size_t)blockIdx.z * NTOK + bm + wr + rl) * ldc + bo + wc + cl;
        *(uint4*)dst = v;
    }
}

// ---------------------------------------------------------------------------
// bf16 MFMA GEMM, 256x256 tile, BK=32, 512 thr = 8 waves (2M x 4N),
// 64KB LDS double-buffered, 2-phase global_load_lds pipeline.
// DUAL mode: grid.z = 0 -> up (A+1024, W+4194304, C=Cp), z = 1 -> gate
// (A, W, C = Cp + 16777216 ushorts). Both plain bf16 stores.
// ---------------------------------------------------------------------------
__global__ __launch_bounds__(512) void gemm256_kernel(
    const ushort* __restrict__ A, int lda,
    const ushort* __restrict__ W, int ldw,
    ushort* __restrict__ Cp, int ldc, int K)
{
    __shared__ ushort lds[2][2][256 * 32];
    const int tid = threadIdx.x;
    const int z = blockIdx.z;
    A  += z ? 0 : 1024;
    W  += z ? 0 : 4194304;
    Cp += z ? 16777216 : 0;
    const int nwg = gridDim.x * gridDim.y;
    const int gy = gridDim.y;
    const int id = blockIdx.y * gridDim.x + blockIdx.x;
    const int swz = (id & 7) * (nwg >> 3) + (id >> 3);
    const int bm = (swz / gy) * 256;
    const int bo = (swz % gy) * 256;

    const int w = tid >> 6, l = tid & 63;
    const int lq = l & 15, lg = l >> 4;
    const int wrow = (w >> 2) * 128, wcol = (w & 3) * 64;

    f32x4 acc[8][4];
#pragma unroll
    for (int i = 0; i < 8; ++i)
#pragma unroll
        for (int j = 0; j < 4; ++j) acc[i][j] = (f32x4){0.f, 0.f, 0.f, 0.f};

    const int srow = w * 32 + (l >> 2);
    const int schunk = (l & 3) ^ ((l >> 3) & 3);
    const ushort* Ag = A + (size_t)(bm + srow) * lda + schunk * 8;
    const ushort* Wg = W + (size_t)(bo + srow) * ldw + schunk * 8;
    const size_t lda16 = (size_t)16 * lda, ldw16 = (size_t)16 * ldw;

    const int nt = K >> 5;
    int cur = 0;
#pragma unroll
    for (int i = 0; i < 2; ++i) {
        gload_lds16(Ag + i * lda16, &lds[0][0][(w * 32 + i * 16) * 32]);
        gload_lds16(Wg + i * ldw16, &lds[0][1][(w * 32 + i * 16) * 32]);
    }
    __syncthreads();
    for (int t = 0; t < nt; ++t) {
        if (t + 1 < nt) {
            const int k0 = (t + 1) * 32;
#pragma unroll
            for (int i = 0; i < 2; ++i) {
                gload_lds16(Ag + k0 + i * lda16, &lds[cur ^ 1][0][(w * 32 + i * 16) * 32]);
                gload_lds16(Wg + k0 + i * ldw16, &lds[cur ^ 1][1][(w * 32 + i * 16) * 32]);
            }
        }
        short8_t af[8], bf[4];
#pragma unroll
        for (int mf = 0; mf < 8; ++mf) {
            const int ra = wrow + mf * 16 + lq;
            af[mf] = *(const short8_t*)&lds[cur][0][ra * 32 + ((lg ^ ((ra >> 1) & 3)) * 8)];
        }
#pragma unroll
        for (int nf = 0; nf < 4; ++nf) {
            const int rb = wcol + nf * 16 + lq;
            bf[nf] = *(const short8_t*)&lds[cur][1][rb * 32 + ((lg ^ ((rb >> 1) & 3)) * 8)];
        }
        __builtin_amdgcn_s_setprio(1);
#pragma unroll
        for (int mf = 0; mf < 8; ++mf)
#pragma unroll
            for (int nf = 0; nf < 4; ++nf)
                acc[mf][nf] = __builtin_amdgcn_mfma_f32_16x16x32_bf16(
                    af[mf], bf[nf], acc[mf][nf], 0, 0, 0);
        __builtin_amdgcn_s_setprio(0);
        __syncthreads();
        cur ^= 1;
    }

    ushort* eb = &lds[0][0][0] + w * 4096;
#pragma unroll
    for (int h = 0; h < 2; ++h) {
#pragma unroll
        for (int mf2 = 0; mf2 < 4; ++mf2)
#pragma unroll
            for (int r = 0; r < 4; ++r)
#pragma unroll
                for (int nf = 0; nf < 4; ++nf) {
                    const int rl = mf2 * 16 + lg * 4 + r;
                    const int cl = nf * 16 + lq;
                    eb[rl * 64 + cl] = f2bf(acc[h * 4 + mf2][nf][r]);
                }
#pragma unroll
        for (int p = 0; p < 8; ++p) {
            const int rl = p * 8 + (l >> 3);
            const int cl = (l & 7) * 8;
            const uint4 v = *(const uint4*)&eb[rl * 64 + cl];
            const size_t row = bm + wrow + h * 64 + rl;
            const size_t col = bo + wcol + cl;
            *(uint4*)(Cp + row * ldc + col) = v;
        }
    }
}

// ---------------------------------------------------------------------------
// Fused qkv GEMM + rope (table-driven), BK=32 dbuf 32KB LDS. grid (32, 8, 3).
// z=0: rope -> Qb bf16 (scaled by log2e/8); z=1: rope -> Kb bf16;
// z=2: transposed bf16 store into Vt [1024][NTOK].
// ---------------------------------------------------------------------------
__global__ __launch_bounds__(256) void qkv_gemm_kernel(
    const ushort* __restrict__ Ain, const ushort* __restrict__ Wall,
    const float2* __restrict__ rtab,
    ushort* __restrict__ Qb, ushort* __restrict__ Kb, ushort* __restrict__ Vt)
{
    __shared__ ushort lds[2][2][128 * 32];
    const int tid = threadIdx.x;
    const int z = blockIdx.z;
    const int nwg = gridDim.x * gridDim.y;
    const int gy = gridDim.y;
    const int id = blockIdx.y * gridDim.x + blockIdx.x;
    const int swz = (id & 7) * (nwg >> 3) + (id >> 3);
    const int bm = (swz / gy) * 128;
    const int bo = (swz % gy) * 128;

    const int w = tid >> 6, l = tid & 63;
    const int lq = l & 15, lg = l >> 4;
    const int wr = (w >> 1) * 64, wc = (w & 1) * 64;

    f32x4 acc[4][4];
#pragma unroll
    for (int i = 0; i < 4; ++i)
#pragma unroll
        for (int j = 0; j < 4; ++j) acc[i][j] = (f32x4){0.f, 0.f, 0.f, 0.f};

    const int srow = w * 32 + (l >> 2);
    const int schunk = (l & 3) ^ ((l >> 3) & 3);
    const ushort* Ag = Ain + z * 1024 + (size_t)(bm + srow) * 3072 + schunk * 8;
    const ushort* Wg = Wall + (size_t)z * 1048576 + (size_t)(bo + srow) * 1024 + schunk * 8;
    const size_t lda16 = (size_t)16 * 3072, ldw16 = (size_t)16 * 1024;

    int cur = 0;
#pragma unroll
    for (int i = 0; i < 2; ++i) {
        gload_lds16(Ag + i * lda16, &lds[0][0][(w * 32 + i * 16) * 32]);
        gload_lds16(Wg + i * ldw16, &lds[0][1][(w * 32 + i * 16) * 32]);
    }
    __syncthreads();
    for (int t = 0; t < 32; ++t) {
        if (t + 1 < 32) {
            const int k0 = (t + 1) * 32;
#pragma unroll
            for (int i = 0; i < 2; ++i) {
                gload_lds16(Ag + k0 + i * lda16, &lds[cur ^ 1][0][(w * 32 + i * 16) * 32]);
                gload_lds16(Wg + k0 + i * ldw16, &lds[cur ^ 1][1][(w * 32 + i * 16) * 32]);
            }
        }
        short8_t af[4], bf[4];
#pragma unroll
        for (int mf = 0; mf < 4; ++mf) {
            const int ra = wr + mf * 16 + lq;
            af[mf] = *(const short8_t*)&lds[cur][0][ra * 32 + ((lg ^ ((ra >> 1) & 3)) * 8)];
            const int rb = wc + mf * 16 + lq;
            bf[mf] = *(const short8_t*)&lds[cur][1][rb * 32 + ((lg ^ ((rb >> 1) & 3)) * 8)];
        }
        __builtin_amdgcn_s_setprio(1);
#pragma unroll
        for (int mf = 0; mf < 4; ++mf)
#pragma unroll
            for (int nf = 0; nf < 4; ++nf)
                acc[mf][nf] = __builtin_amdgcn_mfma_f32_16x16x32_bf16(
                    af[mf], bf[nf], acc[mf][nf], 0, 0, 0);
        __builtin_amdgcn_s_setprio(0);
        __syncthreads();
        cur ^= 1;
    }

    if (z < 2) {
        ushort* Out = z ? Kb : Qb;
        const float scale = z ? 1.0f : 0.18033688f;
        const int cbase = bo + wc;
#pragma unroll
        for (int mf = 0; mf < 4; ++mf)
#pragma unroll
            for (int r = 0; r < 4; ++r) {
                const int row = bm + wr + mf * 16 + lg * 4 + r;
                const int pos = row & 2047;
#pragma unroll
                for (int nf = 0; nf < 2; ++nf) {
                    const int i = nf * 16 + lq;
                    const float2 cs = rtab[pos * 32 + i];
                    const float x1 = acc[mf][nf][r];
                    const float x2 = acc[mf][nf + 2][r];
                    Out[(size_t)row * 1024 + cbase + i]      = f2bf((x1 * cs.x - x2 * cs.y) * scale);
                    Out[(size_t)row * 1024 + cbase + i + 32] = f2bf((x2 * cs.x + x1 * cs.y) * scale);
                }
            }
    } else {
        ushort* eb = &lds[0][0][0] + w * 4096;
#pragma unroll
        for (int mf = 0; mf < 4; ++mf)
#pragma unroll
            for (int r = 0; r < 4; ++r)
#pragma unroll
                for (int nf = 0; nf < 4; ++nf) {
                    const int rl = mf * 16 + lg * 4 + r;
                    const int cl = nf * 16 + lq;
                    eb[cl * 64 + rl] = f2bf(acc[mf][nf][r]);
                }
#pragma unroll
        for (int p = 0; p < 8; ++p) {
            const int rl = p * 8 + (l >> 3);
            const int cl = (l & 7) * 8;
            const uint4 v = *(const uint4*)&eb[rl * 64 + cl];
            *(uint4*)(Vt + (size_t)(bo + wc + rl) * NTOK + bm + wr + cl) = v;
        }
    }
}

// ---------------------------------------------------------------------------
// MFMA flash attention, bf16, KVBLK=128, exp2-domain softmax. Merged pair,
// PARALLEL: 512 thr = 8 waves; waves 0-3 own q0=31-bx', waves 4-7 own q1=bx',
// with bx' = (bh&16) ? 15-bx : bx (anti-correlated per-CU load). Shared dbuf
// K/V LDS staging (each wave stages 8 rows). Grid (16, 32).
// ---------------------------------------------------------------------------
__global__ __launch_bounds__(512) void attn_mfma_kernel(
    const ushort* __restrict__ Qb, const ushort* __restrict__ Kb,
    const ushort* __restrict__ Vt, ushort* __restrict__ atno)
{
    __shared__ ushort Ks[2][2][64 * 64];
    __shared__ ushort Vs[2][2][64 * 64];
    const int bh = blockIdx.y;
    const int b = bh >> 4, h = bh & 15;
    const int tid = threadIdx.x;
    const int w = tid >> 6, l = tid & 63;
    const int g = l >> 4, t = l & 15;
    const int tok0 = b * 2048;
    const int hoff = h * 64;

    const int srow = w * 8 + (l >> 3);
    const int schunk = (l & 7) ^ (l >> 3);
    const ushort* Kg = Kb + (size_t)(tok0 + srow) * 1024 + hoff + schunk * 8;
    const ushort* Vg = Vt + (size_t)(hoff + srow) * NTOK + tok0 + schunk * 8;
    const int ldsbase = w * 512;

    const int srcA = ((g & 1) * 2) * 16 + t;
    const int srcB = srcA + 16;
    const bool hiSel = (g >> 1) != 0;

    const int bx = (bh & 16) ? (15 - (int)blockIdx.x) : (int)blockIdx.x;
    const int q0 = 31 - bx;
    const int q1 = bx;
    const int nt0 = (q0 + 2) >> 1;
    const int qi = w >> 2;
    const int wq = w & 3;
    const int qb = qi ? q1 : q0;
    const int ntq = (qb + 2) >> 1;
    const int qabs = qb * 64 + wq * 16 + t;

    short8_t qf[2];
#pragma unroll
    for (int ks = 0; ks < 2; ++ks)
        qf[ks] = *(const short8_t*)(Qb + (size_t)(tok0 + qabs) * 1024 + hoff + ks * 32 + g * 8);

    float m_run = -3.0e38f, l_run = 0.0f;
    f32x4 oacc[4];
#pragma unroll
    for (int nf = 0; nf < 4; ++nf) oacc[nf] = (f32x4){0.f, 0.f, 0.f, 0.f};

#pragma unroll
    for (int hf = 0; hf < 2; ++hf) {
        gload_lds16(Kg + (size_t)(hf * 64) * 1024, &Ks[0][hf][ldsbase]);
        gload_lds16(Vg + hf * 64, &Vs[0][hf][ldsbase]);
    }
    __syncthreads();

    int buf = 0;
    for (int kt = 0; kt < nt0; ++kt) {
        if (kt + 1 < nt0) {
            const int nk = (kt + 1) * 128;
#pragma unroll
            for (int hf = 0; hf < 2; ++hf) {
                gload_lds16(Kg + (size_t)(nk + hf * 64) * 1024, &Ks[buf ^ 1][hf][ldsbase]);
                gload_lds16(Vg + nk + hf * 64, &Vs[buf ^ 1][hf][ldsbase]);
            }
        }
        if (kt < ntq) {
            f32x4 sa[2][4];
#pragma unroll
            for (int hf = 0; hf < 2; ++hf)
#pragma unroll
                for (int mf = 0; mf < 4; ++mf) sa[hf][mf] = (f32x4){0.f, 0.f, 0.f, 0.f};
            __builtin_amdgcn_s_setprio(1);
#pragma unroll
            for (int hf = 0; hf < 2; ++hf)
#pragma unroll
                for (int ks = 0; ks < 2; ++ks) {
                    const int jc = ks * 4 + g;
#pragma unroll
                    for (int mf = 0; mf < 4; ++mf) {
                        const short8_t kf = *(const short8_t*)&Ks[buf][hf][(mf * 16 + t) * 64 + ((jc ^ (t & 7)) * 8)];
                        sa[hf][mf] = __builtin_amdgcn_mfma_f32_16x16x32_bf16(kf, qf[ks], sa[hf][mf], 0, 0, 0);
                    }
                }
            __builtin_amdgcn_s_setprio(0);

            float p[2][4][4];
            float mloc = -3.0e38f;
            const bool lastTile = (kt == ntq - 1);
#pragma unroll
            for (int hf = 0; hf < 2; ++hf)
#pragma unroll
                for (int mf = 0; mf < 4; ++mf)
#pragma unroll
                    for (int r = 0; r < 4; ++r) {
                        float s = sa[hf][mf][r];
                        if (lastTile && (kt * 128 + hf * 64 + mf * 16 + g * 4 + r) > qabs) s = -3.0e38f;
                        p[hf][mf][r] = s;
                        mloc = fmaxf(mloc, s);
                    }
            mloc = fmaxf(mloc, __shfl_xor(mloc, 16));
            mloc = fmaxf(mloc, __shfl_xor(mloc, 32));
            const float mnew = fmaxf(m_run, mloc);
            float lsum = 0.f;
#pragma unroll
            for (int hf = 0; hf < 2; ++hf)
#pragma unroll
                for (int mf = 0; mf < 4; ++mf)
#pragma unroll
                    for (int r = 0; r < 4; ++r) {
                        const float e = exp2f(p[hf][mf][r] - mnew);
                        p[hf][mf][r] = e;
                        lsum += e;
                    }
            lsum += __shfl_xor(lsum, 16);
            lsum += __shfl_xor(lsum, 32);
            const float fac = exp2f(m_run - mnew);
            l_run = l_run * fac + lsum;
            m_run = mnew;
#pragma unroll
            for (int r = 0; r < 4; ++r) {
                const float fr = __shfl(fac, g * 4 + r);
#pragma unroll
                for (int nf = 0; nf < 4; ++nf) oacc[nf][r] *= fr;
            }
#pragma unroll
            for (int hf = 0; hf < 2; ++hf) {
                uint32_t pk[4][2];
#pragma unroll
                for (int mf = 0; mf < 4; ++mf) {
                    pk[mf][0] = pack2(p[hf][mf][0], p[hf][mf][1]);
                    pk[mf][1] = pack2(p[hf][mf][2], p[hf][mf][3]);
                }
#pragma unroll
                for (int ks = 0; ks < 2; ++ks) {
                    const uint32_t a00 = __shfl(pk[2 * ks][0], srcA);
                    const uint32_t a01 = __shfl(pk[2 * ks][1], srcA);
                    const uint32_t a10 = __shfl(pk[2 * ks + 1][0], srcA);
                    const uint32_t a11 = __shfl(pk[2 * ks + 1][1], srcA);
                    const uint32_t b00 = __shfl(pk[2 * ks][0], srcB);
                    const uint32_t b01 = __shfl(pk[2 * ks][1], srcB);
                    const uint32_t b10 = __shfl(pk[2 * ks + 1][0], srcB);
                    const uint32_t b11 = __shfl(pk[2 * ks + 1][1], srcB);
                    union { uint32_t u[4]; short8_t v; } pa;
                    pa.u[0] = hiSel ? a10 : a00;
                    pa.u[1] = hiSel ? a11 : a01;
                    pa.u[2] = hiSel ? b10 : b00;
                    pa.u[3] = hiSel ? b11 : b01;
                    const int jc = ks * 4 + g;
                    __builtin_amdgcn_s_setprio(1);
#pragma unroll
                    for (int nf = 0; nf < 4; ++nf) {
                        const short8_t vf = *(const short8_t*)&Vs[buf][hf][(nf * 16 + t) * 64 + ((jc ^ (t & 7)) * 8)];
                        oacc[nf] = __builtin_amdgcn_mfma_f32_16x16x32_bf16(pa.v, vf, oacc[nf], 0, 0, 0);
                    }
                    __builtin_amdgcn_s_setprio(0);
                }
            }
        }
        __syncthreads();
        buf ^= 1;
    }

    const float inv = 1.0f / l_run;
#pragma unroll
    for (int r = 0; r < 4; ++r) {
        const float ir = __shfl(inv, g * 4 + r);
        const int orow = tok0 + qb * 64 + wq * 16 + g * 4 + r;
#pragma unroll
        for (int nf = 0; nf < 4; ++nf)
            atno[(size_t)orow * 1024 + hoff + nf * 16 + t] = f2bf(oacc[nf][r] * ir);
    }
}

// ---------------------------------------------------------------------------
// rat_write core: reduce 4 bf16 split-K partials [4][NTOK][1152] + SSM update.
// Per-token precompute (threads 0..47): sA2 = -softplus(A_logit)*log2e,
// sBf = B_proj/(Aneg-eps). FUSE_READ: fused rat_read<2> -> mlp_in bf16.
// ---------------------------------------------------------------------------
template <int FUSE_READ>
__global__ __launch_bounds__(256) void rat_write_kernel(
    const float* __restrict__ res, const ushort* __restrict__ part,
    const float* __restrict__ wab_b, const float* __restrict__ du_w,
    const float* __restrict__ du_b, float* __restrict__ out,
    const float* __restrict__ Wr, const float* __restrict__ gamma,
    const float* __restrict__ beta, ushort* __restrict__ mlp_in)
{
    const int t = blockIdx.x;
    const int tid = threadIdx.x;
    const size_t zs = (size_t)NTOK * 1152;
    const ushort* p0 = part + (size_t)t * 1152;
    __shared__ float sAB[112];
    __shared__ float sdl[8];
    __shared__ float sA2[48];
    __shared__ float sBf[48];
    __shared__ float sBs[16];
    if (tid < 112)
        sAB[tid] = bf2f(p0[1024 + tid]) + bf2f(p0[zs + 1024 + tid])
                 + bf2f(p0[2 * zs + 1024 + tid]) + bf2f(p0[3 * zs + 1024 + tid]) + wab_b[tid];
    if (tid >= 128 && tid < 136) {
        const int j = tid - 128;
        sdl[j] = bf2f(p0[1136 + j]) + bf2f(p0[zs + 1136 + j])
               + bf2f(p0[2 * zs + 1136 + j]) + bf2f(p0[3 * zs + 1136 + j]);
    }
    __syncthreads();
    if (tid < 48) {
        const float Aneg = -softplus_f(sAB[tid]);
        sA2[tid] = Aneg * 1.4426950408889634f;
        sBf[tid] = sAB[48 + tid] / (Aneg - 1e-5f);
    } else if (tid >= 64 && tid < 80) {
        sBs[tid - 64] = sAB[96 + (tid - 64)];
    }
    __syncthreads();
    const float* rp = res + (size_t)t * 4096;
    float* op = out + (size_t)t * 4096;
    float y[4][2];
#pragma unroll
    for (int ii = 0; ii < 4; ++ii) {
        const int hh = tid + 256 * ii;
        const int rh = hh & 15;
        const float4 w0 = *(const float4*)(du_w + hh * 8);
        const float4 w1 = *(const float4*)(du_w + hh * 8 + 4);
        float dacc = du_b[hh];
        dacc += sdl[0] * w0.x + sdl[1] * w0.y + sdl[2] * w0.z + sdl[3] * w0.w;
        dacc += sdl[4] * w1.x + sdl[5] * w1.y + sdl[6] * w1.z + sdl[7] * w1.w;
        const float delta = softplus_f(dacc);
        const float oh = bf2f(p0[hh]) + bf2f(p0[zs + hh]) + bf2f(p0[2 * zs + hh]) + bf2f(p0[3 * zs + hh]);
        const float4 hs = *(const float4*)(rp + hh * 4);
        const float r4[4] = {hs.x, hs.y, hs.z, hs.w};
        float o4[4];
#pragma unroll
        for (int c = 0; c < 3; ++c) {
            const float Abar = exp2f(delta * sA2[rh * 3 + c]);
            o4[c] = r4[c] * Abar + oh * (Abar - 1.0f) * sBf[rh * 3 + c];
        }
        o4[3] = r4[3] + oh * (delta * sBs[rh]);
        *(float4*)(op + hh * 4) = make_float4(o4[0], o4[1], o4[2], o4[3]);
        if (FUSE_READ) {
#pragma unroll
            for (int o = 0; o < 2; ++o) {
                const float4 w = *(const float4*)(Wr + ((size_t)hh * 2 + o) * 4);
                y[ii][o] = o4[0] * w.x + o4[1] * w.y + o4[2] * w.z + o4[3] * w.w;
            }
        }
    }
    if (FUSE_READ) {
        __shared__ float red[4][2][2];
        const int lane = tid & 63, wid = tid >> 6;
#pragma unroll
        for (int o = 0; o < 2; ++o) {
            float s = 0.f, ss = 0.f;
#pragma unroll
            for (int i = 0; i < 4; ++i) { s += y[i][o]; ss += y[i][o] * y[i][o]; }
            for (int off = 32; off > 0; off >>= 1) {
                s += __shfl_down(s, off);
                ss += __shfl_down(ss, off);
            }
            if (lane == 0) { red[wid][o][0] = s; red[wid][o][1] = ss; }
        }
        __syncthreads();
        float mu[2], rs[2];
#pragma unroll
        for (int o = 0; o < 2; ++o) {
            const float s  = red[0][o][0] + red[1][o][0] + red[2][o][0] + red[3][o][0];
            const float ss = red[0][o][1] + red[1][o][1] + red[2][o][1] + red[3][o][1];
            const float m = s * (1.0f / 1024.0f);
            const float v = ss * (1.0f / 1024.0f) - m * m;
            mu[o] = m;
            rs[o] = rsqrtf(v + 1e-5f);
        }
        ushort* mp = mlp_in + (size_t)t * 2048;
#pragma unroll
        for (int i = 0; i < 4; ++i) {
            const int h = tid + 256 * i;
#pragma unroll
            for (int o = 0; o < 2; ++o)
                mp[o * 1024 + h] = f2bf((y[i][o] - mu[o]) * rs[o] * gamma[o * 1024 + h] + beta[o * 1024 + h]);
        }
    }
}

// ---------------------------------------------------------------------------
extern "C" void kernel_launch(void* const* d_in, const int* in_sizes, int n_in,
                              void* d_out, int out_size, void* d_ws, size_t ws_size,
                              hipStream_t stream)
{
    const float* hidden      = (const float*)d_in[0];
    const float* attn_read_w = (const float*)d_in[2];
    const float* attn_read_g = (const float*)d_in[3];
    const float* attn_read_b = (const float*)d_in[4];
    const float* qkv_w       = (const float*)d_in[5];
    const float* attn_wod_w  = (const float*)d_in[6];
    const float* attn_wab_w  = (const float*)d_in[7];
    const float* attn_wab_b  = (const float*)d_in[8];
    const float* attn_du_w   = (const float*)d_in[9];
    const float* attn_du_b   = (const float*)d_in[10];
    const float* mlp_read_w  = (const float*)d_in[11];
    const float* mlp_read_g  = (const float*)d_in[12];
    const float* mlp_read_b  = (const float*)d_in[13];
    const float* mlp_in_w    = (const float*)d_in[14];
    const float* mlp_wod_w   = (const float*)d_in[15];
    const float* mlp_wab_w   = (const float*)d_in[16];
    const float* mlp_wab_b   = (const float*)d_in[17];
    const float* mlp_du_w    = (const float*)d_in[18];
    const float* mlp_du_b    = (const float*)d_in[19];
    float* out = (float*)d_out;
    char* wsb = (char*)d_ws;
    const size_t N = NTOK;

    // ---- workspace layout (bytes), end = 131,858,432 ----
    ushort* qkv_wb  = (ushort*)(wsb + 0);          // 6,291,456
    ushort* wcombA  = (ushort*)(wsb + 6291456);    // 2,359,296 -> 8,650,752
    ushort* mlpin_b = (ushort*)(wsb + 8650752);    // 16,777,216 -> 25,427,968
    ushort* wcombM  = (ushort*)(wsb + 25427968);   // 9,437,184 -> 34,865,152
    float2* rtab    = (float2*)(wsb + 34865152);   // 524,288 -> 35,389,440
    char* R1 = wsb + 35389440;                     // 25,165,824 -> 60,555,264
    char* R2 = wsb + 60555264;                     // 71,303,168 -> 131,858,432
    ushort* qkv_in = (ushort*)R1;
    ushort* mlp_in = (ushort*)R1;
    ushort* Qb   = (ushort*)R2;
    ushort* Kb   = (ushort*)(R2 + 8388608);
    ushort* atno = (ushort*)(R2 + 16777216);
    ushort* Vt   = (ushort*)(R2 + 33554432);
    ushort* pA   = (ushort*)(R2 + 25165824);
    // MLP phase: up_ @R2+0 (33.5MB), gate @R2+33.5MB (33.5MB);
    // after silu_mul (result into up_), pM (37.75MB) overlays dead gate.
    ushort* up_  = (ushort*)R2;
    ushort* gate = (ushort*)(R2 + 33554432);
    ushort* pM   = (ushort*)(R2 + 33554432);

    // ---- weight conversion + rope table ----
    convert_flat_kernel<<<1536, 256, 0, stream>>>(qkv_w, qkv_wb);
    convert_flat_kernel<<<4096, 256, 0, stream>>>(mlp_in_w, mlpin_b);
    build_comb_kernel<<<576, 256, 0, stream>>>(attn_wod_w, attn_wab_w, wcombA, 1024);
    build_comb_kernel<<<2304, 256, 0, stream>>>(mlp_wod_w, mlp_wab_w, wcombM, 4096);
    rope_tab_kernel<<<256, 256, 0, stream>>>(rtab);

    // ---- attention half ----
    rat_read_kernel<3><<<N, 256, 0, stream>>>(hidden, attn_read_w, attn_read_g, attn_read_b, qkv_in);

    qkv_gemm_kernel<<<dim3(32, 8, 3), 256, 0, stream>>>(qkv_in, qkv_wb, rtab, Qb, Kb, Vt);

    attn_mfma_kernel<<<dim3(16, 32), 512, 0, stream>>>(Qb, Kb, Vt, atno);

    mfma_gemm_kernel<4><<<dim3(32, 9, 4), 256, 0, stream>>>(atno, 1024, wcombA, 1024, pA, 1152, nullptr, 256);

    rat_write_kernel<1><<<N, 256, 0, stream>>>(hidden, pA, attn_wab_b, attn_du_w, attn_du_b, out,
                                               mlp_read_w, mlp_read_g, mlp_read_b, mlp_in);

    // ---- MLP half ----
    // dual dispatch: z=0 -> up (A=mlp_in+1024, W=mlpin_b+4194304, C=up_),
    //                z=1 -> gate (A=mlp_in, W=mlpin_b, C=gate)
    gemm256_kernel<<<dim3(16, 16, 2), 512, 0, stream>>>(mlp_in, 2048, mlpin_b, 1024, up_, 4096, 1024);
    silu_mul_kernel<<<8192, 256, 0, stream>>>(gate, up_);

    mfma_gemm_kernel<4><<<dim3(32, 9, 4), 256, 0, stream>>>(up_, 4096, wcombM, 4096, pM, 1152, nullptr, 1024);

    rat_write_kernel<0><<<N, 256, 0, stream>>>(out, pM, mlp_wab_b, mlp_du_w, mlp_du_b, out,
                                               nullptr, nullptr, nullptr, nullptr);
}

// Round 23
// 374.136 us; speedup vs baseline: 1.0188x; 1.0188x over previous
//
#include <hip/hip_runtime.h>
#include <hip/hip_bf16.h>
#include <math.h>
#include <stdint.h>

// ---------------------------------------------------------------------------
// RatLayer forward. BK=32 dbuf 32KB-LDS bf16 MFMA GEMMs (128^2 skinny) +
// 128x256 MLP GEMMs (512 blocks = 2/CU, serial EPI1 -> EPI2 silu fusion),
// fused qkv+rope (table), split-K=4 merged wod+wab GEMMs (bf16 partials)
// reduced inside rat_write (precomputed tables), rat_write+rat_read fusion,
// merged-pair parallel flash attention (KVBLK=128, bx remap).
// H=1024 C=4 RH=16 HS=64 DR=8 M=4096 NH=16 HD=64 A_SIZE=48 B_SIZE=64
// ---------------------------------------------------------------------------

constexpr int NTOK = 4096;

typedef __attribute__((ext_vector_type(8))) short short8_t;
typedef __attribute__((ext_vector_type(4))) float f32x4;

__device__ __forceinline__ ushort f2bf(float f) {
    union { float f; uint32_t u; } v; v.f = f;
    uint32_t r = v.u + 0x7fffu + ((v.u >> 16) & 1u);
    return (ushort)(r >> 16);
}
__device__ __forceinline__ float bf2f(ushort b) {
    union { uint32_t u; float f; } v; v.u = ((uint32_t)b) << 16;
    return v.f;
}
// packed pair convert — compiler lowers to v_cvt_pk_bf16_f32 on gfx950
__device__ __forceinline__ uint32_t pack2(float lo, float hi) {
    union { __hip_bfloat162 h; uint32_t u; } v;
    v.h = __float22bfloat162_rn(make_float2(lo, hi));
    return v.u;
}
__device__ __forceinline__ float softplus_f(float x) {
    return (x > 20.0f) ? x : log1pf(expf(x));
}

__device__ __forceinline__ void gload_lds16(const void* g, void* l) {
    __builtin_amdgcn_global_load_lds(
        (const __attribute__((address_space(1))) uint32_t*)g,
        (__attribute__((address_space(3))) uint32_t*)l,
        16, 0, 0);
}

// ---------------------------------------------------------------------------
// Weight conversion f32 -> bf16; rope table.
// ---------------------------------------------------------------------------
__global__ __launch_bounds__(256) void convert_flat_kernel(
    const float* __restrict__ src, ushort* __restrict__ dst)
{
    const size_t i = ((size_t)blockIdx.x * 256 + threadIdx.x) * 8;
    const float4 a = *(const float4*)(src + i);
    const float4 b = *(const float4*)(src + i + 4);
    union { ushort u[8]; uint4 v; } o;
    o.u[0] = f2bf(a.x); o.u[1] = f2bf(a.y); o.u[2] = f2bf(a.z); o.u[3] = f2bf(a.w);
    o.u[4] = f2bf(b.x); o.u[5] = f2bf(b.y); o.u[6] = f2bf(b.z); o.u[7] = f2bf(b.w);
    *(uint4*)(dst + i) = o.v;
}

// rope table: tab[pos*32 + i] = (cos, sin) of pos * 10000^(-i/32)
__global__ __launch_bounds__(256) void rope_tab_kernel(float2* __restrict__ tab)
{
    const int idx = blockIdx.x * 256 + threadIdx.x;   // < 2048*32
    const int i = idx & 31;
    const int pos = idx >> 5;
    const float inv = expf(-(float)i * (9.210340371976184f / 32.0f));
    float s, c;
    sincosf((float)pos * inv, &s, &c);
    tab[idx] = make_float2(c, s);
}

// combined weight [1152][K]: rows 0..1023 = wod[0..1023]; 1024..1135 = wab;
// 1136..1143 = wod rows 1024..1031 (delta_low); 1144..1151 = zero.
__global__ __launch_bounds__(256) void build_comb_kernel(
    const float* __restrict__ wod, const float* __restrict__ wab,
    ushort* __restrict__ dst, int K)
{
    const size_t i = ((size_t)blockIdx.x * 256 + threadIdx.x) * 8;
    const int row = (int)(i / (size_t)K);
    const int col = (int)(i % (size_t)K);
    const float* src = nullptr;
    if (row < 1024)      src = wod + (size_t)row * K + col;
    else if (row < 1136) src = wab + (size_t)(row - 1024) * K + col;
    else if (row < 1144) src = wod + (size_t)(1024 + row - 1136) * K + col;
    union { ushort u[8]; uint4 v; } o;
    if (src) {
        const float4 a = *(const float4*)(src);
        const float4 b = *(const float4*)(src + 4);
        o.u[0] = f2bf(a.x); o.u[1] = f2bf(a.y); o.u[2] = f2bf(a.z); o.u[3] = f2bf(a.w);
        o.u[4] = f2bf(b.x); o.u[5] = f2bf(b.y); o.u[6] = f2bf(b.z); o.u[7] = f2bf(b.w);
    } else {
        o.v = make_uint4(0, 0, 0, 0);
    }
    *(uint4*)(dst + i) = o.v;
}

// ---------------------------------------------------------------------------
// rat_read: mix + LayerNorm + affine; writes bf16. One block per token.
// ---------------------------------------------------------------------------
template <int NO>
__global__ __launch_bounds__(256) void rat_read_kernel(
    const float* __restrict__ res, const float* __restrict__ W,
    const float* __restrict__ gamma, const float* __restrict__ beta,
    ushort* __restrict__ out)
{
    const int t = blockIdx.x;
    const int tid = threadIdx.x;
    const float* rp = res + (size_t)t * 4096;
    float y[4][NO];
#pragma unroll
    for (int i = 0; i < 4; ++i) {
        const int h = tid + 256 * i;
        const float4 x = *(const float4*)(rp + h * 4);
#pragma unroll
        for (int o = 0; o < NO; ++o) {
            const float4 w = *(const float4*)(W + ((size_t)h * NO + o) * 4);
            y[i][o] = x.x * w.x + x.y * w.y + x.z * w.z + x.w * w.w;
        }
    }
    __shared__ float red[4][NO][2];
    const int lane = tid & 63, wid = tid >> 6;
#pragma unroll
    for (int o = 0; o < NO; ++o) {
        float s = 0.f, ss = 0.f;
#pragma unroll
        for (int i = 0; i < 4; ++i) { s += y[i][o]; ss += y[i][o] * y[i][o]; }
        for (int off = 32; off > 0; off >>= 1) {
            s += __shfl_down(s, off);
            ss += __shfl_down(ss, off);
        }
        if (lane == 0) { red[wid][o][0] = s; red[wid][o][1] = ss; }
    }
    __syncthreads();
    float mu[NO], rs[NO];
#pragma unroll
    for (int o = 0; o < NO; ++o) {
        const float s  = red[0][o][0] + red[1][o][0] + red[2][o][0] + red[3][o][0];
        const float ss = red[0][o][1] + red[1][o][1] + red[2][o][1] + red[3][o][1];
        const float m = s * (1.0f / 1024.0f);
        const float v = ss * (1.0f / 1024.0f) - m * m;
        mu[o] = m;
        rs[o] = rsqrtf(v + 1e-5f);
    }
    ushort* op = out + (size_t)t * (NO * 1024);
#pragma unroll
    for (int i = 0; i < 4; ++i) {
        const int h = tid + 256 * i;
#pragma unroll
        for (int o = 0; o < NO; ++o) {
            op[o * 1024 + h] = f2bf((y[i][o] - mu[o]) * rs[o] * gamma[o * 1024 + h] + beta[o * 1024 + h]);
        }
    }
}

// ---------------------------------------------------------------------------
// BK=32 dbuf bf16 MFMA GEMM, 128x128 tile, 32KB LDS (5 blocks/CU cap),
// gemm256-pattern staging/swizzle. EPI 4: bf16 partial at Cp + z*NTOK*ldc.
// ---------------------------------------------------------------------------
template <int EPI>
__global__ __launch_bounds__(256) void mfma_gemm_kernel(
    const ushort* __restrict__ A, int lda,
    const ushort* __restrict__ W, int ldw,
    void* __restrict__ Cp, int ldc,
    const ushort* __restrict__ U,
    int Kblk)
{
    __shared__ ushort lds[2][2][128 * 32];   // [buf][A/B][row*32+col] = 32KB
    const int tid = threadIdx.x;
    const int nwg = gridDim.x * gridDim.y;
    const int gy = gridDim.y;
    const int id = blockIdx.y * gridDim.x + blockIdx.x;
    const int swz = (id & 7) * (nwg >> 3) + (id >> 3);
    const int bm = (swz / gy) * 128;
    const int bo = (swz % gy) * 128;

    const int w = tid >> 6, l = tid & 63;
    const int lq = l & 15, lg = l >> 4;
    const int wr = (w >> 1) * 64, wc = (w & 1) * 64;

    f32x4 acc[4][4];
#pragma unroll
    for (int i = 0; i < 4; ++i)
#pragma unroll
        for (int j = 0; j < 4; ++j) acc[i][j] = (f32x4){0.f, 0.f, 0.f, 0.f};

    const int srow = w * 32 + (l >> 2);
    const int schunk = (l & 3) ^ ((l >> 3) & 3);
    const ushort* Ag = A + (size_t)(bm + srow) * lda + (size_t)blockIdx.z * Kblk + schunk * 8;
    const ushort* Wg = W + (size_t)(bo + srow) * ldw + (size_t)blockIdx.z * Kblk + schunk * 8;
    const size_t lda16 = (size_t)16 * lda, ldw16 = (size_t)16 * ldw;

    const int nt = Kblk >> 5;
    int cur = 0;
#pragma unroll
    for (int i = 0; i < 2; ++i) {
        gload_lds16(Ag + i * lda16, &lds[0][0][(w * 32 + i * 16) * 32]);
        gload_lds16(Wg + i * ldw16, &lds[0][1][(w * 32 + i * 16) * 32]);
    }
    __syncthreads();
    for (int t = 0; t < nt; ++t) {
        if (t + 1 < nt) {
            const int k0 = (t + 1) * 32;
#pragma unroll
            for (int i = 0; i < 2; ++i) {
                gload_lds16(Ag + k0 + i * lda16, &lds[cur ^ 1][0][(w * 32 + i * 16) * 32]);
                gload_lds16(Wg + k0 + i * ldw16, &lds[cur ^ 1][1][(w * 32 + i * 16) * 32]);
            }
        }
        short8_t af[4], bf[4];
#pragma unroll
        for (int mf = 0; mf < 4; ++mf) {
            const int ra = wr + mf * 16 + lq;
            af[mf] = *(const short8_t*)&lds[cur][0][ra * 32 + ((lg ^ ((ra >> 1) & 3)) * 8)];
            const int rb = wc + mf * 16 + lq;
            bf[mf] = *(const short8_t*)&lds[cur][1][rb * 32 + ((lg ^ ((rb >> 1) & 3)) * 8)];
        }
        __builtin_amdgcn_s_setprio(1);
#pragma unroll
        for (int mf = 0; mf < 4; ++mf)
#pragma unroll
            for (int nf = 0; nf < 4; ++nf)
                acc[mf][nf] = __builtin_amdgcn_mfma_f32_16x16x32_bf16(
                    af[mf], bf[nf], acc[mf][nf], 0, 0, 0);
        __builtin_amdgcn_s_setprio(0);
        __syncthreads();
        cur ^= 1;
    }

    // EPI 4: bf16 partial via wave-local LDS transpose, full uint4 lines.
    ushort* eb = &lds[0][0][0] + w * 4096;
#pragma unroll
    for (int mf = 0; mf < 4; ++mf)
#pragma unroll
        for (int r = 0; r < 4; ++r)
#pragma unroll
            for (int nf = 0; nf < 4; ++nf) {
                const int rl = mf * 16 + lg * 4 + r;
                const int cl = nf * 16 + lq;
                eb[rl * 64 + cl] = f2bf(acc[mf][nf][r]);
            }
#pragma unroll
    for (int p = 0; p < 8; ++p) {
        const int rl = p * 8 + (l >> 3);
        const int cl = (l & 7) * 8;
        const uint4 v = *(const uint4*)&eb[rl * 64 + cl];
        ushort* dst = (ushort*)Cp + ((size_t)blockIdx.z * NTOK + bm + wr + rl) * ldc + bo + wc + cl;
        *(uint4*)dst = v;
    }
}

// ---------------------------------------------------------------------------
// bf16 MFMA GEMM, 128x256 tile (A-rows 128, B-rows 256), BK=32, 512 thr =
// 8 waves (2M x 4N), 48KB staging dbuf inside one 64KB LDS block; grid
// (32, 16) = 512 blocks -> 2 blocks/CU co-residency (hides barrier drain).
// Staging: 24 chunks of 16 rows (A: c<8, B: c>=8), 3 chunks per wave.
// EPI: 1 bf16 store, 2 silu(acc)*U bf16 store.
// ---------------------------------------------------------------------------
template <int EPI>
__global__ __launch_bounds__(512) void gemm256_kernel(
    const ushort* __restrict__ A, int lda,
    const ushort* __restrict__ W, int ldw,
    ushort* __restrict__ Cp, int ldc,
    const ushort* __restrict__ U, int K)
{
    __shared__ ushort lds[32768];            // 64KB: [buf*12288 + row*32+col]
    const int tid = threadIdx.x;
    const int nwg = gridDim.x * gridDim.y;   // 512
    const int gy = gridDim.y;                // 16
    const int id = blockIdx.y * gridDim.x + blockIdx.x;
    const int swz = (id & 7) * (nwg >> 3) + (id >> 3);
    const int bm = (swz / gy) * 128;
    const int bo = (swz % gy) * 256;

    const int w = tid >> 6, l = tid & 63;
    const int lq = l & 15, lg = l >> 4;
    const int wrow = (w >> 2) * 64, wcol = (w & 3) * 64;

    f32x4 acc[4][4];
#pragma unroll
    for (int i = 0; i < 4; ++i)
#pragma unroll
        for (int j = 0; j < 4; ++j) acc[i][j] = (f32x4){0.f, 0.f, 0.f, 0.f};

    const int schunk = (l & 3) ^ ((l >> 3) & 3);
    const ushort* Ab = A + (size_t)(bm + (l >> 2)) * lda + schunk * 8;
    const ushort* Wb = W + (size_t)(bo + (l >> 2)) * ldw + schunk * 8;

    const int nt = K >> 5;
    int cur = 0;
#pragma unroll
    for (int i = 0; i < 3; ++i) {
        const int c = w * 3 + i;
        const ushort* src = (c < 8) ? Ab + (size_t)(c * 16) * lda
                                    : Wb + (size_t)((c - 8) * 16) * ldw;
        gload_lds16(src, &lds[c * 512]);
    }
    __syncthreads();
    for (int t = 0; t < nt; ++t) {
        if (t + 1 < nt) {
            const int k0 = (t + 1) * 32;
#pragma unroll
            for (int i = 0; i < 3; ++i) {
                const int c = w * 3 + i;
                const ushort* src = (c < 8) ? Ab + (size_t)(c * 16) * lda + k0
                                            : Wb + (size_t)((c - 8) * 16) * ldw + k0;
                gload_lds16(src, &lds[(cur ^ 1) * 12288 + c * 512]);
            }
        }
        short8_t af[4], bf[4];
#pragma unroll
        for (int mf = 0; mf < 4; ++mf) {
            const int ra = wrow + mf * 16 + lq;
            af[mf] = *(const short8_t*)&lds[cur * 12288 + ra * 32 + ((lg ^ ((ra >> 1) & 3)) * 8)];
            const int rb = wcol + mf * 16 + lq;
            bf[mf] = *(const short8_t*)&lds[cur * 12288 + (128 + rb) * 32 + ((lg ^ ((rb >> 1) & 3)) * 8)];
        }
        __builtin_amdgcn_s_setprio(1);
#pragma unroll
        for (int mf = 0; mf < 4; ++mf)
#pragma unroll
            for (int nf = 0; nf < 4; ++nf)
                acc[mf][nf] = __builtin_amdgcn_mfma_f32_16x16x32_bf16(
                    af[mf], bf[nf], acc[mf][nf], 0, 0, 0);
        __builtin_amdgcn_s_setprio(0);
        __syncthreads();
        cur ^= 1;
    }

    // epilogue: wave-local LDS transpose, full uint4 lines.
    ushort* eb = lds + w * 4096;
#pragma unroll
    for (int mf = 0; mf < 4; ++mf)
#pragma unroll
        for (int r = 0; r < 4; ++r)
#pragma unroll
            for (int nf = 0; nf < 4; ++nf) {
                const int rl = mf * 16 + lg * 4 + r;
                const int cl = nf * 16 + lq;
                eb[rl * 64 + cl] = f2bf(acc[mf][nf][r]);
            }
#pragma unroll
    for (int p = 0; p < 8; ++p) {
        const int rl = p * 8 + (l >> 3);
        const int cl = (l & 7) * 8;
        const uint4 v = *(const uint4*)&eb[rl * 64 + cl];
        const size_t row = bm + wrow + rl;
        const size_t col = bo + wcol + cl;
        if (EPI == 1) {
            *(uint4*)(Cp + row * ldc + col) = v;
        } else {
            const uint4 uv = *(const uint4*)(U + row * ldc + col);
            union { uint4 v; ushort u[8]; } g, uu, o;
            g.v = v; uu.v = uv;
#pragma unroll
            for (int e = 0; e < 8; ++e) {
                const float gf = bf2f(g.u[e]);
                o.u[e] = f2bf(gf / (1.0f + __expf(-gf)) * bf2f(uu.u[e]));
            }
            *(uint4*)(Cp + row * ldc + col) = o.v;
        }
    }
}

// ---------------------------------------------------------------------------
// Fused qkv GEMM + rope (table-driven), BK=32 dbuf 32KB LDS. grid (32, 8, 3).
// z=0: rope -> Qb bf16 (scaled by log2e/8); z=1: rope -> Kb bf16;
// z=2: transposed bf16 store into Vt [1024][NTOK].
// ---------------------------------------------------------------------------
__global__ __launch_bounds__(256) void qkv_gemm_kernel(
    const ushort* __restrict__ Ain, const ushort* __restrict__ Wall,
    const float2* __restrict__ rtab,
    ushort* __restrict__ Qb, ushort* __restrict__ Kb, ushort* __restrict__ Vt)
{
    __shared__ ushort lds[2][2][128 * 32];
    const int tid = threadIdx.x;
    const int z = blockIdx.z;
    const int nwg = gridDim.x * gridDim.y;
    const int gy = gridDim.y;
    const int id = blockIdx.y * gridDim.x + blockIdx.x;
    const int swz = (id & 7) * (nwg >> 3) + (id >> 3);
    const int bm = (swz / gy) * 128;
    const int bo = (swz % gy) * 128;

    const int w = tid >> 6, l = tid & 63;
    const int lq = l & 15, lg = l >> 4;
    const int wr = (w >> 1) * 64, wc = (w & 1) * 64;

    f32x4 acc[4][4];
#pragma unroll
    for (int i = 0; i < 4; ++i)
#pragma unroll
        for (int j = 0; j < 4; ++j) acc[i][j] = (f32x4){0.f, 0.f, 0.f, 0.f};

    const int srow = w * 32 + (l >> 2);
    const int schunk = (l & 3) ^ ((l >> 3) & 3);
    const ushort* Ag = Ain + z * 1024 + (size_t)(bm + srow) * 3072 + schunk * 8;
    const ushort* Wg = Wall + (size_t)z * 1048576 + (size_t)(bo + srow) * 1024 + schunk * 8;
    const size_t lda16 = (size_t)16 * 3072, ldw16 = (size_t)16 * 1024;

    int cur = 0;
#pragma unroll
    for (int i = 0; i < 2; ++i) {
        gload_lds16(Ag + i * lda16, &lds[0][0][(w * 32 + i * 16) * 32]);
        gload_lds16(Wg + i * ldw16, &lds[0][1][(w * 32 + i * 16) * 32]);
    }
    __syncthreads();
    for (int t = 0; t < 32; ++t) {
        if (t + 1 < 32) {
            const int k0 = (t + 1) * 32;
#pragma unroll
            for (int i = 0; i < 2; ++i) {
                gload_lds16(Ag + k0 + i * lda16, &lds[cur ^ 1][0][(w * 32 + i * 16) * 32]);
                gload_lds16(Wg + k0 + i * ldw16, &lds[cur ^ 1][1][(w * 32 + i * 16) * 32]);
            }
        }
        short8_t af[4], bf[4];
#pragma unroll
        for (int mf = 0; mf < 4; ++mf) {
            const int ra = wr + mf * 16 + lq;
            af[mf] = *(const short8_t*)&lds[cur][0][ra * 32 + ((lg ^ ((ra >> 1) & 3)) * 8)];
            const int rb = wc + mf * 16 + lq;
            bf[mf] = *(const short8_t*)&lds[cur][1][rb * 32 + ((lg ^ ((rb >> 1) & 3)) * 8)];
        }
        __builtin_amdgcn_s_setprio(1);
#pragma unroll
        for (int mf = 0; mf < 4; ++mf)
#pragma unroll
            for (int nf = 0; nf < 4; ++nf)
                acc[mf][nf] = __builtin_amdgcn_mfma_f32_16x16x32_bf16(
                    af[mf], bf[nf], acc[mf][nf], 0, 0, 0);
        __builtin_amdgcn_s_setprio(0);
        __syncthreads();
        cur ^= 1;
    }

    if (z < 2) {
        ushort* Out = z ? Kb : Qb;
        const float scale = z ? 1.0f : 0.18033688f;
        const int cbase = bo + wc;
#pragma unroll
        for (int mf = 0; mf < 4; ++mf)
#pragma unroll
            for (int r = 0; r < 4; ++r) {
                const int row = bm + wr + mf * 16 + lg * 4 + r;
                const int pos = row & 2047;
#pragma unroll
                for (int nf = 0; nf < 2; ++nf) {
                    const int i = nf * 16 + lq;
                    const float2 cs = rtab[pos * 32 + i];
                    const float x1 = acc[mf][nf][r];
                    const float x2 = acc[mf][nf + 2][r];
                    Out[(size_t)row * 1024 + cbase + i]      = f2bf((x1 * cs.x - x2 * cs.y) * scale);
                    Out[(size_t)row * 1024 + cbase + i + 32] = f2bf((x2 * cs.x + x1 * cs.y) * scale);
                }
            }
    } else {
        ushort* eb = &lds[0][0][0] + w * 4096;
#pragma unroll
        for (int mf = 0; mf < 4; ++mf)
#pragma unroll
            for (int r = 0; r < 4; ++r)
#pragma unroll
                for (int nf = 0; nf < 4; ++nf) {
                    const int rl = mf * 16 + lg * 4 + r;
                    const int cl = nf * 16 + lq;
                    eb[cl * 64 + rl] = f2bf(acc[mf][nf][r]);
                }
#pragma unroll
        for (int p = 0; p < 8; ++p) {
            const int rl = p * 8 + (l >> 3);
            const int cl = (l & 7) * 8;
            const uint4 v = *(const uint4*)&eb[rl * 64 + cl];
            *(uint4*)(Vt + (size_t)(bo + wc + rl) * NTOK + bm + wr + cl) = v;
        }
    }
}

// ---------------------------------------------------------------------------
// MFMA flash attention, bf16, KVBLK=128, exp2-domain softmax. Merged pair,
// PARALLEL: 512 thr = 8 waves; waves 0-3 own q0=31-bx', waves 4-7 own q1=bx',
// with bx' = (bh&16) ? 15-bx : bx (anti-correlated per-CU load). Shared dbuf
// K/V LDS staging (each wave stages 8 rows). Grid (16, 32).
// ---------------------------------------------------------------------------
__global__ __launch_bounds__(512) void attn_mfma_kernel(
    const ushort* __restrict__ Qb, const ushort* __restrict__ Kb,
    const ushort* __restrict__ Vt, ushort* __restrict__ atno)
{
    __shared__ ushort Ks[2][2][64 * 64];
    __shared__ ushort Vs[2][2][64 * 64];
    const int bh = blockIdx.y;
    const int b = bh >> 4, h = bh & 15;
    const int tid = threadIdx.x;
    const int w = tid >> 6, l = tid & 63;
    const int g = l >> 4, t = l & 15;
    const int tok0 = b * 2048;
    const int hoff = h * 64;

    const int srow = w * 8 + (l >> 3);
    const int schunk = (l & 7) ^ (l >> 3);
    const ushort* Kg = Kb + (size_t)(tok0 + srow) * 1024 + hoff + schunk * 8;
    const ushort* Vg = Vt + (size_t)(hoff + srow) * NTOK + tok0 + schunk * 8;
    const int ldsbase = w * 512;

    const int srcA = ((g & 1) * 2) * 16 + t;
    const int srcB = srcA + 16;
    const bool hiSel = (g >> 1) != 0;

    const int bx = (bh & 16) ? (15 - (int)blockIdx.x) : (int)blockIdx.x;
    const int q0 = 31 - bx;
    const int q1 = bx;
    const int nt0 = (q0 + 2) >> 1;
    const int qi = w >> 2;
    const int wq = w & 3;
    const int qb = qi ? q1 : q0;
    const int ntq = (qb + 2) >> 1;
    const int qabs = qb * 64 + wq * 16 + t;

    short8_t qf[2];
#pragma unroll
    for (int ks = 0; ks < 2; ++ks)
        qf[ks] = *(const short8_t*)(Qb + (size_t)(tok0 + qabs) * 1024 + hoff + ks * 32 + g * 8);

    float m_run = -3.0e38f, l_run = 0.0f;
    f32x4 oacc[4];
#pragma unroll
    for (int nf = 0; nf < 4; ++nf) oacc[nf] = (f32x4){0.f, 0.f, 0.f, 0.f};

#pragma unroll
    for (int hf = 0; hf < 2; ++hf) {
        gload_lds16(Kg + (size_t)(hf * 64) * 1024, &Ks[0][hf][ldsbase]);
        gload_lds16(Vg + hf * 64, &Vs[0][hf][ldsbase]);
    }
    __syncthreads();

    int buf = 0;
    for (int kt = 0; kt < nt0; ++kt) {
        if (kt + 1 < nt0) {
            const int nk = (kt + 1) * 128;
#pragma unroll
            for (int hf = 0; hf < 2; ++hf) {
                gload_lds16(Kg + (size_t)(nk + hf * 64) * 1024, &Ks[buf ^ 1][hf][ldsbase]);
                gload_lds16(Vg + nk + hf * 64, &Vs[buf ^ 1][hf][ldsbase]);
            }
        }
        if (kt < ntq) {
            f32x4 sa[2][4];
#pragma unroll
            for (int hf = 0; hf < 2; ++hf)
#pragma unroll
                for (int mf = 0; mf < 4; ++mf) sa[hf][mf] = (f32x4){0.f, 0.f, 0.f, 0.f};
            __builtin_amdgcn_s_setprio(1);
#pragma unroll
            for (int hf = 0; hf < 2; ++hf)
#pragma unroll
                for (int ks = 0; ks < 2; ++ks) {
                    const int jc = ks * 4 + g;
#pragma unroll
                    for (int mf = 0; mf < 4; ++mf) {
                        const short8_t kf = *(const short8_t*)&Ks[buf][hf][(mf * 16 + t) * 64 + ((jc ^ (t & 7)) * 8)];
                        sa[hf][mf] = __builtin_amdgcn_mfma_f32_16x16x32_bf16(kf, qf[ks], sa[hf][mf], 0, 0, 0);
                    }
                }
            __builtin_amdgcn_s_setprio(0);

            float p[2][4][4];
            float mloc = -3.0e38f;
            const bool lastTile = (kt == ntq - 1);
#pragma unroll
            for (int hf = 0; hf < 2; ++hf)
#pragma unroll
                for (int mf = 0; mf < 4; ++mf)
#pragma unroll
                    for (int r = 0; r < 4; ++r) {
                        float s = sa[hf][mf][r];
                        if (lastTile && (kt * 128 + hf * 64 + mf * 16 + g * 4 + r) > qabs) s = -3.0e38f;
                        p[hf][mf][r] = s;
                        mloc = fmaxf(mloc, s);
                    }
            mloc = fmaxf(mloc, __shfl_xor(mloc, 16));
            mloc = fmaxf(mloc, __shfl_xor(mloc, 32));
            const float mnew = fmaxf(m_run, mloc);
            float lsum = 0.f;
#pragma unroll
            for (int hf = 0; hf < 2; ++hf)
#pragma unroll
                for (int mf = 0; mf < 4; ++mf)
#pragma unroll
                    for (int r = 0; r < 4; ++r) {
                        const float e = exp2f(p[hf][mf][r] - mnew);
                        p[hf][mf][r] = e;
                        lsum += e;
                    }
            lsum += __shfl_xor(lsum, 16);
            lsum += __shfl_xor(lsum, 32);
            const float fac = exp2f(m_run - mnew);
            l_run = l_run * fac + lsum;
            m_run = mnew;
#pragma unroll
            for (int r = 0; r < 4; ++r) {
                const float fr = __shfl(fac, g * 4 + r);
#pragma unroll
                for (int nf = 0; nf < 4; ++nf) oacc[nf][r] *= fr;
            }
#pragma unroll
            for (int hf = 0; hf < 2; ++hf) {
                uint32_t pk[4][2];
#pragma unroll
                for (int mf = 0; mf < 4; ++mf) {
                    pk[mf][0] = pack2(p[hf][mf][0], p[hf][mf][1]);
                    pk[mf][1] = pack2(p[hf][mf][2], p[hf][mf][3]);
                }
#pragma unroll
                for (int ks = 0; ks < 2; ++ks) {
                    const uint32_t a00 = __shfl(pk[2 * ks][0], srcA);
                    const uint32_t a01 = __shfl(pk[2 * ks][1], srcA);
                    const uint32_t a10 = __shfl(pk[2 * ks + 1][0], srcA);
                    const uint32_t a11 = __shfl(pk[2 * ks + 1][1], srcA);
                    const uint32_t b00 = __shfl(pk[2 * ks][0], srcB);
                    const uint32_t b01 = __shfl(pk[2 * ks][1], srcB);
                    const uint32_t b10 = __shfl(pk[2 * ks + 1][0], srcB);
                    const uint32_t b11 = __shfl(pk[2 * ks + 1][1], srcB);
                    union { uint32_t u[4]; short8_t v; } pa;
                    pa.u[0] = hiSel ? a10 : a00;
                    pa.u[1] = hiSel ? a11 : a01;
                    pa.u[2] = hiSel ? b10 : b00;
                    pa.u[3] = hiSel ? b11 : b01;
                    const int jc = ks * 4 + g;
                    __builtin_amdgcn_s_setprio(1);
#pragma unroll
                    for (int nf = 0; nf < 4; ++nf) {
                        const short8_t vf = *(const short8_t*)&Vs[buf][hf][(nf * 16 + t) * 64 + ((jc ^ (t & 7)) * 8)];
                        oacc[nf] = __builtin_amdgcn_mfma_f32_16x16x32_bf16(pa.v, vf, oacc[nf], 0, 0, 0);
                    }
                    __builtin_amdgcn_s_setprio(0);
                }
            }
        }
        __syncthreads();
        buf ^= 1;
    }

    const float inv = 1.0f / l_run;
#pragma unroll
    for (int r = 0; r < 4; ++r) {
        const float ir = __shfl(inv, g * 4 + r);
        const int orow = tok0 + qb * 64 + wq * 16 + g * 4 + r;
#pragma unroll
        for (int nf = 0; nf < 4; ++nf)
            atno[(size_t)orow * 1024 + hoff + nf * 16 + t] = f2bf(oacc[nf][r] * ir);
    }
}

// ---------------------------------------------------------------------------
// rat_write core: reduce 4 bf16 split-K partials [4][NTOK][1152] + SSM update.
// Per-token precompute (threads 0..47): sA2 = -softplus(A_logit)*log2e,
// sBf = B_proj/(Aneg-eps). FUSE_READ: fused rat_read<2> -> mlp_in bf16.
// ---------------------------------------------------------------------------
template <int FUSE_READ>
__global__ __launch_bounds__(256) void rat_write_kernel(
    const float* __restrict__ res, const ushort* __restrict__ part,
    const float* __restrict__ wab_b, const float* __restrict__ du_w,
    const float* __restrict__ du_b, float* __restrict__ out,
    const float* __restrict__ Wr, const float* __restrict__ gamma,
    const float* __restrict__ beta, ushort* __restrict__ mlp_in)
{
    const int t = blockIdx.x;
    const int tid = threadIdx.x;
    const size_t zs = (size_t)NTOK * 1152;
    const ushort* p0 = part + (size_t)t * 1152;
    __shared__ float sAB[112];
    __shared__ float sdl[8];
    __shared__ float sA2[48];
    __shared__ float sBf[48];
    __shared__ float sBs[16];
    if (tid < 112)
        sAB[tid] = bf2f(p0[1024 + tid]) + bf2f(p0[zs + 1024 + tid])
                 + bf2f(p0[2 * zs + 1024 + tid]) + bf2f(p0[3 * zs + 1024 + tid]) + wab_b[tid];
    if (tid >= 128 && tid < 136) {
        const int j = tid - 128;
        sdl[j] = bf2f(p0[1136 + j]) + bf2f(p0[zs + 1136 + j])
               + bf2f(p0[2 * zs + 1136 + j]) + bf2f(p0[3 * zs + 1136 + j]);
    }
    __syncthreads();
    if (tid < 48) {
        const float Aneg = -softplus_f(sAB[tid]);
        sA2[tid] = Aneg * 1.4426950408889634f;
        sBf[tid] = sAB[48 + tid] / (Aneg - 1e-5f);
    } else if (tid >= 64 && tid < 80) {
        sBs[tid - 64] = sAB[96 + (tid - 64)];
    }
    __syncthreads();
    const float* rp = res + (size_t)t * 4096;
    float* op = out + (size_t)t * 4096;
    float y[4][2];
#pragma unroll
    for (int ii = 0; ii < 4; ++ii) {
        const int hh = tid + 256 * ii;
        const int rh = hh & 15;
        const float4 w0 = *(const float4*)(du_w + hh * 8);
        const float4 w1 = *(const float4*)(du_w + hh * 8 + 4);
        float dacc = du_b[hh];
        dacc += sdl[0] * w0.x + sdl[1] * w0.y + sdl[2] * w0.z + sdl[3] * w0.w;
        dacc += sdl[4] * w1.x + sdl[5] * w1.y + sdl[6] * w1.z + sdl[7] * w1.w;
        const float delta = softplus_f(dacc);
        const float oh = bf2f(p0[hh]) + bf2f(p0[zs + hh]) + bf2f(p0[2 * zs + hh]) + bf2f(p0[3 * zs + hh]);
        const float4 hs = *(const float4*)(rp + hh * 4);
        const float r4[4] = {hs.x, hs.y, hs.z, hs.w};
        float o4[4];
#pragma unroll
        for (int c = 0; c < 3; ++c) {
            const float Abar = exp2f(delta * sA2[rh * 3 + c]);
            o4[c] = r4[c] * Abar + oh * (Abar - 1.0f) * sBf[rh * 3 + c];
        }
        o4[3] = r4[3] + oh * (delta * sBs[rh]);
        *(float4*)(op + hh * 4) = make_float4(o4[0], o4[1], o4[2], o4[3]);
        if (FUSE_READ) {
#pragma unroll
            for (int o = 0; o < 2; ++o) {
                const float4 w = *(const float4*)(Wr + ((size_t)hh * 2 + o) * 4);
                y[ii][o] = o4[0] * w.x + o4[1] * w.y + o4[2] * w.z + o4[3] * w.w;
            }
        }
    }
    if (FUSE_READ) {
        __shared__ float red[4][2][2];
        const int lane = tid & 63, wid = tid >> 6;
#pragma unroll
        for (int o = 0; o < 2; ++o) {
            float s = 0.f, ss = 0.f;
#pragma unroll
            for (int i = 0; i < 4; ++i) { s += y[i][o]; ss += y[i][o] * y[i][o]; }
            for (int off = 32; off > 0; off >>= 1) {
                s += __shfl_down(s, off);
                ss += __shfl_down(ss, off);
            }
            if (lane == 0) { red[wid][o][0] = s; red[wid][o][1] = ss; }
        }
        __syncthreads();
        float mu[2], rs[2];
#pragma unroll
        for (int o = 0; o < 2; ++o) {
            const float s  = red[0][o][0] + red[1][o][0] + red[2][o][0] + red[3][o][0];
            const float ss = red[0][o][1] + red[1][o][1] + red[2][o][1] + red[3][o][1];
            const float m = s * (1.0f / 1024.0f);
            const float v = ss * (1.0f / 1024.0f) - m * m;
            mu[o] = m;
            rs[o] = rsqrtf(v + 1e-5f);
        }
        ushort* mp = mlp_in + (size_t)t * 2048;
#pragma unroll
        for (int i = 0; i < 4; ++i) {
            const int h = tid + 256 * i;
#pragma unroll
            for (int o = 0; o < 2; ++o)
                mp[o * 1024 + h] = f2bf((y[i][o] - mu[o]) * rs[o] * gamma[o * 1024 + h] + beta[o * 1024 + h]);
        }
    }
}

// ---------------------------------------------------------------------------
extern "C" void kernel_launch(void* const* d_in, const int* in_sizes, int n_in,
                              void* d_out, int out_size, void* d_ws, size_t ws_size,
                              hipStream_t stream)
{
    const float* hidden      = (const float*)d_in[0];
    const float* attn_read_w = (const float*)d_in[2];
    const float* attn_read_g = (const float*)d_in[3];
    const float* attn_read_b = (const float*)d_in[4];
    const float* qkv_w       = (const float*)d_in[5];
    const float* attn_wod_w  = (const float*)d_in[6];
    const float* attn_wab_w  = (const float*)d_in[7];
    const float* attn_wab_b  = (const float*)d_in[8];
    const float* attn_du_w   = (const float*)d_in[9];
    const float* attn_du_b   = (const float*)d_in[10];
    const float* mlp_read_w  = (const float*)d_in[11];
    const float* mlp_read_g  = (const float*)d_in[12];
    const float* mlp_read_b  = (const float*)d_in[13];
    const float* mlp_in_w    = (const float*)d_in[14];
    const float* mlp_wod_w   = (const float*)d_in[15];
    const float* mlp_wab_w   = (const float*)d_in[16];
    const float* mlp_wab_b   = (const float*)d_in[17];
    const float* mlp_du_w    = (const float*)d_in[18];
    const float* mlp_du_b    = (const float*)d_in[19];
    float* out = (float*)d_out;
    char* wsb = (char*)d_ws;
    const size_t N = NTOK;

    // ---- workspace layout (bytes), end = 131,858,432 ----
    ushort* qkv_wb  = (ushort*)(wsb + 0);          // 6,291,456
    ushort* wcombA  = (ushort*)(wsb + 6291456);    // 2,359,296 -> 8,650,752
    ushort* mlpin_b = (ushort*)(wsb + 8650752);    // 16,777,216 -> 25,427,968
    ushort* wcombM  = (ushort*)(wsb + 25427968);   // 9,437,184 -> 34,865,152
    float2* rtab    = (float2*)(wsb + 34865152);   // 524,288 -> 35,389,440
    char* R1 = wsb + 35389440;                     // 25,165,824 -> 60,555,264
    char* R2 = wsb + 60555264;                     // 71,303,168 -> 131,858,432
    ushort* qkv_in = (ushort*)R1;
    ushort* mlp_in = (ushort*)R1;
    ushort* Qb   = (ushort*)R2;
    ushort* Kb   = (ushort*)(R2 + 8388608);
    ushort* atno = (ushort*)(R2 + 16777216);
    ushort* Vt   = (ushort*)(R2 + 33554432);
    ushort* pA   = (ushort*)(R2 + 25165824);
    ushort* upb  = (ushort*)R2;
    ushort* up_  = (ushort*)(R2 + 33554432);
    ushort* pM   = (ushort*)(R2 + 33554432);

    // ---- weight conversion + rope table ----
    convert_flat_kernel<<<1536, 256, 0, stream>>>(qkv_w, qkv_wb);
    convert_flat_kernel<<<4096, 256, 0, stream>>>(mlp_in_w, mlpin_b);
    build_comb_kernel<<<576, 256, 0, stream>>>(attn_wod_w, attn_wab_w, wcombA, 1024);
    build_comb_kernel<<<2304, 256, 0, stream>>>(mlp_wod_w, mlp_wab_w, wcombM, 4096);
    rope_tab_kernel<<<256, 256, 0, stream>>>(rtab);

    // ---- attention half ----
    rat_read_kernel<3><<<N, 256, 0, stream>>>(hidden, attn_read_w, attn_read_g, attn_read_b, qkv_in);

    qkv_gemm_kernel<<<dim3(32, 8, 3), 256, 0, stream>>>(qkv_in, qkv_wb, rtab, Qb, Kb, Vt);

    attn_mfma_kernel<<<dim3(16, 32), 512, 0, stream>>>(Qb, Kb, Vt, atno);

    mfma_gemm_kernel<4><<<dim3(32, 9, 4), 256, 0, stream>>>(atno, 1024, wcombA, 1024, pA, 1152, nullptr, 256);

    rat_write_kernel<1><<<N, 256, 0, stream>>>(hidden, pA, attn_wab_b, attn_du_w, attn_du_b, out,
                                               mlp_read_w, mlp_read_g, mlp_read_b, mlp_in);

    // ---- MLP half ----
    gemm256_kernel<1><<<dim3(32, 16), 512, 0, stream>>>(mlp_in + 1024, 2048, mlpin_b + 4194304, 1024, up_, 4096, nullptr, 1024);
    gemm256_kernel<2><<<dim3(32, 16), 512, 0, stream>>>(mlp_in, 2048, mlpin_b, 1024, upb, 4096, up_, 1024);

    mfma_gemm_kernel<4><<<dim3(32, 9, 4), 256, 0, stream>>>(upb, 4096, wcombM, 4096, pM, 1152, nullptr, 1024);

    rat_write_kernel<0><<<N, 256, 0, stream>>>(out, pM, mlp_wab_b, mlp_du_w, mlp_du_b, out,
                                               nullptr, nullptr, nullptr, nullptr);
}